// Round 16
// baseline (464.148 us; speedup 1.0000x reference)
//
#include <hip/hip_runtime.h>
#include <math.h>

// Problem constants: B_eff=32, T=2048, D=1024, S=4.
#define NSTREAMS 4
#define SINKHORN_ITERS 10
#define TAU 0.05f
#define N4_SHIFT 19        // T*D/4 = 524288 float4 per (b,stream) slice

typedef float f32x4 __attribute__((ext_vector_type(4)));

// ---------------------------------------------------------------------------
// Kernel 1 (1 block, lane 0): Sinkhorn + softmaxes, folded into one matrix:
//   M[i][j] = h_res[i][j] + h_post[i] * h_pre[j]
// 16 floats to d_ws. Proven off-critical-path and numerically exact (R10).
// ---------------------------------------------------------------------------
__global__ void coeff_kernel(const float* __restrict__ res_logits,
                             const float* __restrict__ pre_logits,
                             const float* __restrict__ post_logits,
                             float* __restrict__ Mout) {
    if (threadIdx.x != 0 || blockIdx.x != 0) return;

    float scaled[NSTREAMS][NSTREAMS];
    float mx = -INFINITY;
    #pragma unroll
    for (int i = 0; i < NSTREAMS; ++i)
        #pragma unroll
        for (int j = 0; j < NSTREAMS; ++j) {
            float sv = res_logits[i * NSTREAMS + j] * (1.0f / TAU);
            scaled[i][j] = sv;
            mx = fmaxf(mx, sv);
        }
    #pragma unroll
    for (int i = 0; i < NSTREAMS; ++i)
        #pragma unroll
        for (int j = 0; j < NSTREAMS; ++j)
            scaled[i][j] -= mx;

    const float logm = -logf((float)NSTREAMS);
    float uu[NSTREAMS] = {0.f, 0.f, 0.f, 0.f};
    float vv[NSTREAMS] = {0.f, 0.f, 0.f, 0.f};

    for (int it = 0; it < SINKHORN_ITERS; ++it) {
        #pragma unroll
        for (int i = 0; i < NSTREAMS; ++i) {
            float m = -INFINITY;
            #pragma unroll
            for (int j = 0; j < NSTREAMS; ++j) m = fmaxf(m, scaled[i][j] + vv[j]);
            float s = 0.f;
            #pragma unroll
            for (int j = 0; j < NSTREAMS; ++j) s += expf(scaled[i][j] + vv[j] - m);
            uu[i] = logm - (m + logf(s));
        }
        #pragma unroll
        for (int j = 0; j < NSTREAMS; ++j) {
            float m = -INFINITY;
            #pragma unroll
            for (int i = 0; i < NSTREAMS; ++i) m = fmaxf(m, scaled[i][j] + uu[i]);
            float s = 0.f;
            #pragma unroll
            for (int i = 0; i < NSTREAMS; ++i) s += expf(scaled[i][j] + uu[i] - m);
            vv[j] = logm - (m + logf(s));
        }
    }

    float hres[NSTREAMS][NSTREAMS];
    #pragma unroll
    for (int i = 0; i < NSTREAMS; ++i)
        #pragma unroll
        for (int j = 0; j < NSTREAMS; ++j)
            hres[i][j] = expf(scaled[i][j] + uu[i] + vv[j]) * (float)NSTREAMS;

    float hpre[NSTREAMS], hpost[NSTREAMS];
    {
        float m = -INFINITY;
        #pragma unroll
        for (int k = 0; k < NSTREAMS; ++k) m = fmaxf(m, pre_logits[k]);
        float e[NSTREAMS], s = 0.f;
        #pragma unroll
        for (int k = 0; k < NSTREAMS; ++k) { e[k] = expf(pre_logits[k] - m); s += e[k]; }
        #pragma unroll
        for (int k = 0; k < NSTREAMS; ++k) hpre[k] = e[k] / s;
    }
    {
        float m = -INFINITY;
        #pragma unroll
        for (int k = 0; k < NSTREAMS; ++k) m = fmaxf(m, post_logits[k]);
        float e[NSTREAMS], s = 0.f;
        #pragma unroll
        for (int k = 0; k < NSTREAMS; ++k) { e[k] = expf(post_logits[k] - m); s += e[k]; }
        #pragma unroll
        for (int k = 0; k < NSTREAMS; ++k) hpost[k] = e[k] / s;
    }

    #pragma unroll
    for (int i = 0; i < NSTREAMS; ++i)
        #pragma unroll
        for (int j = 0; j < NSTREAMS; ++j)
            Mout[i * NSTREAMS + j] = hres[i][j] + hpost[i] * hpre[j];
}

// ---------------------------------------------------------------------------
// Kernel 2: contiguity-restructured mix (H1 discriminator).
// Block = 4 waves, owns 1024 float4 per stream of one b-slice (64 KB LDS).
//   Phase 1: wave w stages stream w's 1024 items = 16 KB CONTIGUOUS run
//            (16 x b128 loads back-to-back per lane).
//   Phase 2: wave i mixes rows from LDS and stores output stream i as a
//            16 KB CONTIGUOUS run.
// Every global access is copy-shaped per wave; the 8 MiB-stride gather/
// scatter moves into LDS (negligible: ~1 GB over 78 TB/s aggregate).
// 2 blocks/CU (128 KB of 160 KB LDS) lets neighbor blocks overlap phases.
// ---------------------------------------------------------------------------
__global__ __launch_bounds__(256) void mix_kernel(const f32x4* __restrict__ in,
                                                  f32x4* __restrict__ out,
                                                  const float* __restrict__ M) {
    __shared__ f32x4 lds[4][1024];   // 64 KB

    const int bid   = blockIdx.x;        // 0..4095
    const int b     = bid >> 9;          // b-slice (8)
    const int chunk = bid & 511;         // 512 chunks per slice
    const int r0    = chunk << 10;       // 1024 items per chunk
    const int w     = threadIdx.x >> 6;  // wave 0..3
    const int l     = threadIdx.x & 63;  // lane
    const int base  = (b << 2) << N4_SHIFT;

    // Phase 1: wave w stages stream w — one contiguous 16 KB run.
    const f32x4* src = in + base + (w << N4_SHIFT) + r0;
    #pragma unroll
    for (int k = 0; k < 16; ++k) {
        const int item = (k << 6) + l;
        lds[w][item] = src[item];
    }
    __syncthreads();

    // Phase 2: wave w computes OUTPUT stream w (row w of M), contiguous store.
    const float m0 = M[w * 4 + 0];
    const float m1 = M[w * 4 + 1];
    const float m2 = M[w * 4 + 2];
    const float m3 = M[w * 4 + 3];

    f32x4* dst = out + base + (w << N4_SHIFT) + r0;
    #pragma unroll
    for (int k = 0; k < 16; ++k) {
        const int item = (k << 6) + l;
        f32x4 o = m0 * lds[0][item];
        o += m1 * lds[1][item];
        o += m2 * lds[2][item];
        o += m3 * lds[3][item];
        dst[item] = o;
    }
}

extern "C" void kernel_launch(void* const* d_in, const int* in_sizes, int n_in,
                              void* d_out, int out_size, void* d_ws, size_t ws_size,
                              hipStream_t stream) {
    const float* streams     = (const float*)d_in[0];
    const float* h_res_log   = (const float*)d_in[1];
    const float* h_pre_log   = (const float*)d_in[2];
    const float* h_post_log  = (const float*)d_in[3];
    float* out = (float*)d_out;
    float* M   = (float*)d_ws;   // 16 floats

    coeff_kernel<<<1, 64, 0, stream>>>(h_res_log, h_pre_log, h_post_log, M);

    // 4096 blocks x 256 threads; each block: 1024 items x 4 streams.
    mix_kernel<<<4096, 256, 0, stream>>>((const f32x4*)streams, (f32x4*)out, M);
}